// Round 2
// baseline (364.155 us; speedup 1.0000x reference)
//
#include <hip/hip_runtime.h>
#include <math.h>

#define N_SITES 64
#define N_MID   62
#define BD      32
#define BATCH   32768

// One thread per batch element. 64-thread blocks; both candidate matrices for
// the current site staged in LDS (8 KB), per-lane selected by the spin bit.
// State is rescaled by its max every site (log accumulated) so the amplitude
// never overflows fp32 -> finite log-amplitude matching the fp64 reference.
__global__ __launch_bounds__(64) void mps_kernel(
    const float* __restrict__ t_first,  // (2,1,32)
    const float* __restrict__ t_mid,    // (62,2,32,32)
    const float* __restrict__ t_last,   // (2,32,1)
    const int*   __restrict__ x,        // (32768,64), values in {-1,+1}
    float* __restrict__ out)            // (32768,)
{
    __shared__ float Tld[2 * BD * BD];  // 8 KB: T0 then T1 for current site

    const int tid = threadIdx.x;
    const int b   = blockIdx.x * 64 + tid;

    // Build the 64-bit occupancy mask for this element: bit s = (x[b,s] > 0).
    unsigned long long mask = 0ull;
    {
        const int4* xr = (const int4*)(x + (size_t)b * N_SITES);
        #pragma unroll
        for (int c = 0; c < 16; ++c) {
            int4 v = xr[c];
            unsigned long long m = 0ull;
            m |= (unsigned long long)(v.x > 0) << (4 * c + 0);
            m |= (unsigned long long)(v.y > 0) << (4 * c + 1);
            m |= (unsigned long long)(v.z > 0) << (4 * c + 2);
            m |= (unsigned long long)(v.w > 0) << (4 * c + 3);
            mask |= m;
        }
    }

    // state = t_first[bit0, 0, :]
    float s[BD];
    {
        const float* tf = t_first + ((mask & 1ull) ? BD : 0);
        #pragma unroll
        for (int j = 0; j < BD; ++j) s[j] = tf[j];
    }

    float logacc = 0.0f;  // running sum of log(scale)

    for (int site = 0; site < N_MID; ++site) {
        // Stage both matrices for this site: 2048 floats = 512 float4,
        // 64 threads -> 8 float4 each, coalesced.
        {
            const float4* src = (const float4*)(t_mid + (size_t)site * 2 * BD * BD);
            float4* dst = (float4*)Tld;
            #pragma unroll
            for (int c = 0; c < 8; ++c)
                dst[c * 64 + tid] = src[c * 64 + tid];
        }
        __syncthreads();

        // Select matrix by bit (site+1): bits 1..62 index t_mid[0..61].
        const float4* Tm4 =
            (const float4*)(Tld + (((mask >> (site + 1)) & 1ull) ? BD * BD : 0));

        float acc[BD];
        #pragma unroll
        for (int j = 0; j < BD; ++j) acc[j] = 0.0f;

        #pragma unroll
        for (int i = 0; i < BD; ++i) {
            const float si = s[i];
            #pragma unroll
            for (int jc = 0; jc < 8; ++jc) {
                float4 t = Tm4[i * 8 + jc];
                acc[4 * jc + 0] = fmaf(si, t.x, acc[4 * jc + 0]);
                acc[4 * jc + 1] = fmaf(si, t.y, acc[4 * jc + 1]);
                acc[4 * jc + 2] = fmaf(si, t.z, acc[4 * jc + 2]);
                acc[4 * jc + 3] = fmaf(si, t.w, acc[4 * jc + 3]);
            }
        }

        // Rescale: all values are strictly positive (inputs are U[0,1)).
        float mx = acc[0];
        #pragma unroll
        for (int j = 1; j < BD; ++j) mx = fmaxf(mx, acc[j]);
        const float inv = 1.0f / mx;
        #pragma unroll
        for (int j = 0; j < BD; ++j) s[j] = acc[j] * inv;
        logacc += logf(mx);

        __syncthreads();  // protect Tld before next site's staging
    }

    // amp = dot(state, t_last[bit63, :, 0]); out = sum(log scales) + log(amp)
    {
        const float* tl = t_last + (((mask >> 63) & 1ull) ? BD : 0);
        float amp = 0.0f;
        #pragma unroll
        for (int j = 0; j < BD; ++j) amp = fmaf(s[j], tl[j], amp);
        out[b] = logacc + logf(amp);
    }
}

extern "C" void kernel_launch(void* const* d_in, const int* in_sizes, int n_in,
                              void* d_out, int out_size, void* d_ws, size_t ws_size,
                              hipStream_t stream) {
    const float* t_first = (const float*)d_in[0];
    const float* t_mid   = (const float*)d_in[1];
    const float* t_last  = (const float*)d_in[2];
    const int*   x       = (const int*)d_in[3];
    float* out           = (float*)d_out;

    hipLaunchKernelGGL(mps_kernel, dim3(BATCH / 64), dim3(64), 0, stream,
                       t_first, t_mid, t_last, x, out);
}

// Round 3
// 101.799 us; speedup vs baseline: 3.5772x; 3.5772x over previous
//
#include <hip/hip_runtime.h>
#include <math.h>

#define N_MID 62
#define BATCH 32768

typedef float f32x4 __attribute__((ext_vector_type(4)));
typedef short s16x8 __attribute__((ext_vector_type(8)));

// fp32 -> bf16 (round-half-up; inputs are positive finite)
__device__ __forceinline__ short f2bf(float f) {
    unsigned u = __float_as_uint(f);
    return (short)((u + 0x8000u) >> 16);
}

// ---------------- Kernel 1: spin masks (bit s = x[b,s] > 0) ----------------
__global__ __launch_bounds__(256) void mask_kernel(const int* __restrict__ x,
                                                   unsigned long long* __restrict__ masks) {
    int b = blockIdx.x * 256 + threadIdx.x;
    const int4* xr = (const int4*)(x + (size_t)b * 64);
    unsigned long long m = 0ull;
    #pragma unroll
    for (int c = 0; c < 16; ++c) {
        int4 v = xr[c];
        m |= (unsigned long long)(v.x > 0) << (4 * c + 0);
        m |= (unsigned long long)(v.y > 0) << (4 * c + 1);
        m |= (unsigned long long)(v.z > 0) << (4 * c + 2);
        m |= (unsigned long long)(v.w > 0) << (4 * c + 3);
    }
    masks[b] = m;
}

// ------- Kernel 2: t_mid fp32 -> bf16, pre-swizzled into B-frag order -------
// B-frag layout for mfma_f32_16x16x32_bf16: lane l holds B[k=(l>>4)*8+j][n=l&15].
// wsB block f = ((site*2+branch)*2 + coltile): 64 lanes x 8 bf16 contiguous.
__global__ __launch_bounds__(64) void bswz_kernel(const float* __restrict__ t_mid,
                                                  short* __restrict__ wsB) {
    int f = blockIdx.x;  // 0..247
    int l = threadIdx.x;
    int t = f & 1, pb = (f >> 1) & 1, s = f >> 2;
    int n = 16 * t + (l & 15);
    int kb = (l >> 4) * 8;
    const float* src = t_mid + (size_t)(s * 2 + pb) * 32 * 32;  // [k][n]
    s16x8 v;
    #pragma unroll
    for (int j = 0; j < 8; ++j) v[j] = f2bf(src[(kb + j) * 32 + n]);
    ((s16x8*)wsB)[f * 64 + l] = v;
}

// ---------------------------- Main MFMA kernel -----------------------------
// One wave = 16 batch elements. States live in MFMA C-layout:
//   value (row m, col n) in lane 16*(m>>2) + (n&15), reg (m&3), tile (n>>4).
// Per site: states -> LDS (bf16, row-major pad 40) -> A-frag; 4 MFMAs (2
// branches x 2 col-tiles); per-reg select by spin bit; pow2 rescale every 4.
#define RSTRIDE 40  // bf16 elements per LDS row (pad 32 -> 40 = 80 B, 16B-aligned)

__global__ __launch_bounds__(256) void mps_mfma_kernel(
    const float* __restrict__ t_first,
    const float* __restrict__ t_last,
    const unsigned long long* __restrict__ masks,
    const short* __restrict__ wsB,
    float* __restrict__ out)
{
    __shared__ short Sl[4][16 * RSTRIDE];  // per-wave private 1280 B

    const int tid  = threadIdx.x;
    const int w    = tid >> 6;       // wave in block
    const int l    = tid & 63;       // lane
    const int q    = l >> 4;         // lane group 0..3
    const int p    = l & 15;         // position in group
    const int base = (blockIdx.x * 4 + w) * 16;  // batch tile base

    short* S = &Sl[w][0];

    // Masks for the 4 rows this lane's C-regs cover (rows 4q+r).
    unsigned long long mrot[4];
    #pragma unroll
    for (int r = 0; r < 4; ++r) mrot[r] = masks[base + 4 * q + r];

    // Init state from t_first[bit0]: st[t][r] = value (row 4q+r, col 16t+p)
    float st[2][4];
    #pragma unroll
    for (int r = 0; r < 4; ++r) {
        const float* tf = t_first + ((mrot[r] & 1ull) ? 32 : 0);
        st[0][r] = tf[p];
        st[1][r] = tf[16 + p];
        mrot[r] >>= 1;  // next bit to consume = site 1's bit
    }

    int expsum[4] = {0, 0, 0, 0};

    // B-frag pointers: 4 frags x 64 lanes x 8 shorts per site.
    const s16x8* bp = (const s16x8*)wsB + l;
    s16x8 bcur[2][2], bnext[2][2];
    #pragma unroll
    for (int pb = 0; pb < 2; ++pb)
        #pragma unroll
        for (int t = 0; t < 2; ++t)
            bcur[pb][t] = bp[(pb * 2 + t) * 64];
    bp += 256;

    const f32x4 cz = {0.f, 0.f, 0.f, 0.f};

    for (int s = 0; s < N_MID; ++s) {
        // Prefetch next site's B-frags (L1/L2-resident).
        if (s < N_MID - 1) {
            #pragma unroll
            for (int pb = 0; pb < 2; ++pb)
                #pragma unroll
                for (int t = 0; t < 2; ++t)
                    bnext[pb][t] = bp[(pb * 2 + t) * 64];
            bp += 256;
        }

        // State (C-layout regs) -> LDS bf16 [m][k], row stride RSTRIDE.
        #pragma unroll
        for (int r = 0; r < 4; ++r) {
            S[(4 * q + r) * RSTRIDE + p]      = f2bf(st[0][r]);
            S[(4 * q + r) * RSTRIDE + 16 + p] = f2bf(st[1][r]);
        }
        __asm__ volatile("s_waitcnt lgkmcnt(0)" ::: "memory");

        // A-frag: lane reads row m=p, k = 8q..8q+7 (16 B, aligned).
        s16x8 afrag = *(const s16x8*)(S + p * RSTRIDE + 8 * q);

        // Both branches, both col-tiles.
        f32x4 y0t0 = __builtin_amdgcn_mfma_f32_16x16x32_bf16(afrag, bcur[0][0], cz, 0, 0, 0);
        f32x4 y0t1 = __builtin_amdgcn_mfma_f32_16x16x32_bf16(afrag, bcur[0][1], cz, 0, 0, 0);
        f32x4 y1t0 = __builtin_amdgcn_mfma_f32_16x16x32_bf16(afrag, bcur[1][0], cz, 0, 0, 0);
        f32x4 y1t1 = __builtin_amdgcn_mfma_f32_16x16x32_bf16(afrag, bcur[1][1], cz, 0, 0, 0);

        // Per-row branch select by this site's spin bit.
        #pragma unroll
        for (int r = 0; r < 4; ++r) {
            bool hi = (mrot[r] & 1ull) != 0;
            st[0][r] = hi ? y1t0[r] : y0t0[r];
            st[1][r] = hi ? y1t1[r] : y0t1[r];
            mrot[r] >>= 1;
        }

        // Power-of-2 per-row rescale every 4 sites (exact log bookkeeping).
        if ((s & 3) == 3) {
            #pragma unroll
            for (int r = 0; r < 4; ++r) {
                float mx = fmaxf(st[0][r], st[1][r]);
                #pragma unroll
                for (int off = 1; off < 16; off <<= 1)
                    mx = fmaxf(mx, __shfl_xor(mx, off, 16));
                int ex = (int)((__float_as_uint(mx) >> 23) & 0xFF) - 127;
                float scale = __uint_as_float((unsigned)(127 - ex) << 23);
                st[0][r] *= scale;
                st[1][r] *= scale;
                expsum[r] += ex;
            }
        }

        #pragma unroll
        for (int pb = 0; pb < 2; ++pb)
            #pragma unroll
            for (int t = 0; t < 2; ++t)
                bcur[pb][t] = bnext[pb][t];
    }

    // Epilogue: amp_r = dot(state_r, t_last[bit63]); reduce over 16 lanes.
    float tl00 = t_last[p],      tl01 = t_last[16 + p];
    float tl10 = t_last[32 + p], tl11 = t_last[48 + p];
    float amp[4];
    #pragma unroll
    for (int r = 0; r < 4; ++r) {
        bool hi = (mrot[r] & 1ull) != 0;  // bit 63 after 63 shifts
        float prod = st[0][r] * (hi ? tl10 : tl00) + st[1][r] * (hi ? tl11 : tl01);
        #pragma unroll
        for (int off = 1; off < 16; off <<= 1)
            prod += __shfl_xor(prod, off, 16);
        amp[r] = prod;
    }

    if (p < 4) {
        float a = (p == 0) ? amp[0] : (p == 1) ? amp[1] : (p == 2) ? amp[2] : amp[3];
        int   e = (p == 0) ? expsum[0] : (p == 1) ? expsum[1] : (p == 2) ? expsum[2] : expsum[3];
        out[base + 4 * q + p] = logf(a) + 0.69314718055994531f * (float)e;
    }
}

extern "C" void kernel_launch(void* const* d_in, const int* in_sizes, int n_in,
                              void* d_out, int out_size, void* d_ws, size_t ws_size,
                              hipStream_t stream) {
    const float* t_first = (const float*)d_in[0];
    const float* t_mid   = (const float*)d_in[1];
    const float* t_last  = (const float*)d_in[2];
    const int*   x       = (const int*)d_in[3];
    float* out           = (float*)d_out;

    unsigned long long* masks = (unsigned long long*)d_ws;            // 256 KB
    short* wsB = (short*)((char*)d_ws + (size_t)BATCH * 8);           // 248 KB

    hipLaunchKernelGGL(mask_kernel, dim3(BATCH / 256), dim3(256), 0, stream, x, masks);
    hipLaunchKernelGGL(bswz_kernel, dim3(N_MID * 4), dim3(64), 0, stream, t_mid, wsB);
    hipLaunchKernelGGL(mps_mfma_kernel, dim3(BATCH / 64), dim3(256), 0, stream,
                       t_first, t_last, masks, wsB, out);
}